// Round 1
// baseline (2361.399 us; speedup 1.0000x reference)
//
#include <hip/hip_runtime.h>

#define HIDDEN  64
#define NGATES  256     // 4*HIDDEN
#define T_LEN   4096
#define CHUNK   32
#define MLP_HID 40
#define HP      68      // h_hist row pitch (floats): 272B = 16B-aligned rows
#define W1P     68      // W1 LDS row pitch
#define ZP      41      // z LDS row pitch (odd -> conflict-free column reads)

__device__ __forceinline__ float fast_sigmoid(float x) {
    // 1/(1+exp(-x)) ; exp via v_exp_f32 (2^x), rcp via v_rcp_f32. Safe at +-inf.
    float e = __builtin_amdgcn_exp2f(x * -1.4426950408889634f);
    return __builtin_amdgcn_rcpf(1.0f + e);
}
__device__ __forceinline__ float fast_tanh(float x) {
    // 1 - 2/(exp(2x)+1): saturates correctly (no inf/inf NaN) at both extremes.
    float e = __builtin_amdgcn_exp2f(x * 2.8853900817779268f);
    return 1.0f - 2.0f * __builtin_amdgcn_rcpf(1.0f + e);
}

__global__ __launch_bounds__(256, 1)
void lstm_mlp_kernel(const float* __restrict__ inputs,
                     const float* __restrict__ W_ih,
                     const float* __restrict__ W_hh,
                     const float* __restrict__ b_ih,
                     const float* __restrict__ b_hh,
                     const float* __restrict__ W1,
                     const float* __restrict__ b1,
                     const float* __restrict__ W2,
                     const float* __restrict__ b2,
                     float* __restrict__ out)
{
    __shared__ __align__(16) float x_lds[T_LEN];          // 16 KB: whole input row
    __shared__ __align__(16) float h_buf[HIDDEN];
    __shared__ __align__(16) float a_buf[NGATES];
    __shared__ __align__(16) float h_hist[CHUNK * HP];    // h history for fused MLP
    __shared__ __align__(16) float w1_lds[MLP_HID * W1P];
    __shared__ float b1_lds[MLP_HID];
    __shared__ float w2_lds[MLP_HID];
    __shared__ float z_lds[CHUNK * ZP];

    const int tid = threadIdx.x;
    const int b   = blockIdx.x;

    // ---- prologue: stage inputs row + W1/b1/W2 into LDS, W_hh row into regs ----
    const float4* in4 = (const float4*)(inputs + (size_t)b * T_LEN);
    float4* x4 = (float4*)x_lds;
    #pragma unroll
    for (int r = 0; r < 4; ++r) x4[tid + 256 * r] = in4[tid + 256 * r];

    float4 wr[16];                                        // W_hh[tid, 0:64]
    const float4* whh4 = (const float4*)(W_hh + tid * HIDDEN);
    #pragma unroll
    for (int q = 0; q < 16; ++q) wr[q] = whh4[q];

    const float wih  = W_ih[tid];
    const float bias = b_ih[tid] + b_hh[tid];
    const float b2v  = b2[0];

    for (int p = tid; p < MLP_HID * 65; p += 256) {
        int row = p / 65, col = p - row * 65;
        w1_lds[row * W1P + col] = W1[p];
    }
    if (tid < MLP_HID) { b1_lds[tid] = b1[tid]; w2_lds[tid] = W2[tid]; }
    if (tid < HIDDEN)  h_buf[tid] = 0.0f;
    float c = 0.0f;
    __syncthreads();

    float* outb = out + (size_t)b * T_LEN;

    for (int t = 0; t < T_LEN; ++t) {
        // ---- gate phase: thread j computes gate j (dot of h with its W_hh row) ----
        float xv   = x_lds[t];                            // broadcast
        float acc0 = fmaf(xv, wih, bias);                 // x_proj contribution
        float acc1 = 0.f, acc2 = 0.f, acc3 = 0.f;
        const float4* h4 = (const float4*)h_buf;          // broadcast b128 reads
        #pragma unroll
        for (int q = 0; q < 16; ++q) {
            float4 hv = h4[q];
            acc0 = fmaf(hv.x, wr[q].x, acc0);
            acc1 = fmaf(hv.y, wr[q].y, acc1);
            acc2 = fmaf(hv.z, wr[q].z, acc2);
            acc3 = fmaf(hv.w, wr[q].w, acc3);
        }
        float gate = (acc0 + acc1) + (acc2 + acc3);
        // groups of 64 threads -> wave-uniform branch: i,f,o sigmoid; g tanh
        float a = ((tid >> 6) == 2) ? fast_tanh(gate) : fast_sigmoid(gate);
        a_buf[tid] = a;
        __syncthreads();

        // ---- update phase: wave 0 owns c/h (lane k = hidden unit k) ----
        if (tid < HIDDEN) {
            float gi = a_buf[tid];
            float gf = a_buf[tid + 64];
            float gg = a_buf[tid + 128];
            float go = a_buf[tid + 192];
            c = fmaf(gf, c, gi * gg);
            float hn = go * fast_tanh(c);
            h_buf[tid] = hn;
            h_hist[(t & (CHUNK - 1)) * HP + tid] = hn;
        }
        __syncthreads();

        // ---- fused MLP head every CHUNK steps ----
        if ((t & (CHUNK - 1)) == (CHUNK - 1)) {
            int tbase = t - (CHUNK - 1);
            int tl = tid >> 3, j0 = tid & 7;              // 32 t-rows x 8 j-lanes
            float4 hh[16];
            const float4* hr = (const float4*)(h_hist + tl * HP);
            #pragma unroll
            for (int q = 0; q < 16; ++q) hh[q] = hr[q];
            float xc = x_lds[tbase + tl];
            #pragma unroll
            for (int jj = 0; jj < 5; ++jj) {
                int j = j0 + 8 * jj;
                const float4* w1r = (const float4*)(w1_lds + j * W1P);
                float a0 = b1_lds[j], a1 = 0.f, a2 = 0.f, a3 = 0.f;
                #pragma unroll
                for (int q = 0; q < 16; ++q) {
                    float4 wv = w1r[q];
                    a0 = fmaf(hh[q].x, wv.x, a0);
                    a1 = fmaf(hh[q].y, wv.y, a1);
                    a2 = fmaf(hh[q].z, wv.z, a2);
                    a3 = fmaf(hh[q].w, wv.w, a3);
                }
                float zacc = ((a0 + a1) + (a2 + a3)) + xc * w1_lds[j * W1P + 64];
                z_lds[tl * ZP + j] = fast_sigmoid(zacc);
            }
            __syncthreads();
            if (tid < CHUNK) {                            // 32 lanes reduce 40 z's
                float y = b2v;
                #pragma unroll
                for (int j = 0; j < MLP_HID; ++j)
                    y = fmaf(w2_lds[j], z_lds[tid * ZP + j], y);
                outb[tbase + tid] = y;
            }
            // no trailing barrier needed: next write to z_lds/h_hist is
            // separated by multiple future barriers.
        }
    }
}

extern "C" void kernel_launch(void* const* d_in, const int* in_sizes, int n_in,
                              void* d_out, int out_size, void* d_ws, size_t ws_size,
                              hipStream_t stream) {
    const float* inputs = (const float*)d_in[0];
    const float* W_ih   = (const float*)d_in[1];
    const float* W_hh   = (const float*)d_in[2];
    const float* b_ih   = (const float*)d_in[3];
    const float* b_hh   = (const float*)d_in[4];
    const float* W1     = (const float*)d_in[5];
    const float* b1     = (const float*)d_in[6];
    const float* W2     = (const float*)d_in[7];
    const float* b2     = (const float*)d_in[8];
    float* out = (float*)d_out;

    lstm_mlp_kernel<<<dim3(256), dim3(256), 0, stream>>>(
        inputs, W_ih, W_hh, b_ih, b_hh, W1, b1, W2, b2, out);
}

// Round 2
// 1728.614 us; speedup vs baseline: 1.3661x; 1.3661x over previous
//
#include <hip/hip_runtime.h>

#define HIDDEN  64
#define T_LEN   4096
#define CHUNK   32
#define MLP_HID 40
#define HP      68      // h_hist row pitch (floats): 272B = 16B-aligned rows
#define W1P     68      // W1 LDS row pitch
#define ZP      41      // z LDS row pitch (odd -> conflict-free column reads)

__device__ __forceinline__ float fast_sigmoid(float x) {
    float e = __builtin_amdgcn_exp2f(x * -1.4426950408889634f);
    return __builtin_amdgcn_rcpf(1.0f + e);
}
__device__ __forceinline__ float fast_tanh(float x) {
    // 1 - 2/(exp(2x)+1): saturates correctly at both extremes.
    float e = __builtin_amdgcn_exp2f(x * 2.8853900817779268f);
    return 1.0f - 2.0f * __builtin_amdgcn_rcpf(1.0f + e);
}

// quad-lane butterfly pieces: xor1 = quad_perm[1,0,3,2]=0xB1, xor2 = [2,3,0,1]=0x4E
__device__ __forceinline__ float dpp_xor1(float v) {
    return __int_as_float(__builtin_amdgcn_update_dpp(
        0, __float_as_int(v), 0xB1, 0xF, 0xF, true));
}
__device__ __forceinline__ float dpp_xor2(float v) {
    return __int_as_float(__builtin_amdgcn_update_dpp(
        0, __float_as_int(v), 0x4E, 0xF, 0xF, true));
}

__global__ __launch_bounds__(256, 1)
void lstm_mlp_kernel(const float* __restrict__ inputs,
                     const float* __restrict__ W_ih,
                     const float* __restrict__ W_hh,
                     const float* __restrict__ b_ih,
                     const float* __restrict__ b_hh,
                     const float* __restrict__ W1,
                     const float* __restrict__ b1,
                     const float* __restrict__ W2,
                     const float* __restrict__ b2,
                     float* __restrict__ out)
{
    __shared__ __align__(16) float x_lds[T_LEN];          // 16 KB: whole input row
    __shared__ __align__(16) float h_hist[CHUNK * HP];    // rolling h(t) rows
    __shared__ __align__(16) float w1_lds[MLP_HID * W1P];
    __shared__ float b1_lds[MLP_HID];
    __shared__ float w2_lds[MLP_HID];
    __shared__ float z_lds[CHUNK * ZP];

    const int tid = threadIdx.x;
    const int b   = blockIdx.x;
    const int w   = tid >> 6;        // wave 0..3
    const int l   = tid & 63;
    const int r   = l >> 2;          // unit-in-wave 0..15
    const int q   = l & 3;           // K-chunk 0..3 (h[16q:16q+16))
    const int u   = 16 * w + r;      // hidden unit owned by this quad

    // ---- prologue ----
    const float4* in4 = (const float4*)(inputs + (size_t)b * T_LEN);
    float4* x4 = (float4*)x_lds;
    #pragma unroll
    for (int rr = 0; rr < 4; ++rr) x4[tid + 256 * rr] = in4[tid + 256 * rr];

    // W_hh[j*64+u][16q .. 16q+16) for the 4 gate types j
    float4 wreg[4][4];
    float wih[4], bias[4];
    #pragma unroll
    for (int j = 0; j < 4; ++j) {
        const int g = j * 64 + u;
        const float4* p = (const float4*)(W_hh + g * HIDDEN + 16 * q);
        #pragma unroll
        for (int m = 0; m < 4; ++m) wreg[j][m] = p[m];
        wih[j]  = W_ih[g];
        bias[j] = b_ih[g] + b_hh[g];
    }
    const float b2v = b2[0];

    for (int p = tid; p < MLP_HID * 65; p += 256) {
        int row = p / 65, col = p - row * 65;
        w1_lds[row * W1P + col] = W1[p];
    }
    if (tid < MLP_HID) { b1_lds[tid] = b1[tid]; w2_lds[tid] = W2[tid]; }
    if (tid < HIDDEN)  h_hist[31 * HP + tid] = 0.0f;      // h(-1) = 0 in row 31
    float c = 0.0f;
    __syncthreads();

    float* outb = out + (size_t)b * T_LEN;
    const float* hrow_rd = h_hist + 31 * HP;              // h(t-1) row

    for (int t = 0; t < T_LEN; ++t) {
        // ---- gate partials: 4 gates x 16-wide K-slice (64 FMA) ----
        const float4* h4 = (const float4*)(hrow_rd + 16 * q);
        float4 hv0 = h4[0], hv1 = h4[1], hv2 = h4[2], hv3 = h4[3];
        float xv = x_lds[t];

        float acc[4];
        #pragma unroll
        for (int j = 0; j < 4; ++j) {
            float a0 = hv0.x * wreg[j][0].x, a1 = hv0.y * wreg[j][0].y;
            float a2 = hv0.z * wreg[j][0].z, a3 = hv0.w * wreg[j][0].w;
            a0 = fmaf(hv1.x, wreg[j][1].x, a0); a1 = fmaf(hv1.y, wreg[j][1].y, a1);
            a2 = fmaf(hv1.z, wreg[j][1].z, a2); a3 = fmaf(hv1.w, wreg[j][1].w, a3);
            a0 = fmaf(hv2.x, wreg[j][2].x, a0); a1 = fmaf(hv2.y, wreg[j][2].y, a1);
            a2 = fmaf(hv2.z, wreg[j][2].z, a2); a3 = fmaf(hv2.w, wreg[j][2].w, a3);
            a0 = fmaf(hv3.x, wreg[j][3].x, a0); a1 = fmaf(hv3.y, wreg[j][3].y, a1);
            a2 = fmaf(hv3.z, wreg[j][3].z, a2); a3 = fmaf(hv3.w, wreg[j][3].w, a3);
            acc[j] = (a0 + a1) + (a2 + a3);
        }
        // ---- quad butterfly: every lane gets all 4 full gate sums ----
        #pragma unroll
        for (int j = 0; j < 4; ++j) {
            acc[j] += dpp_xor1(acc[j]);
            acc[j] += dpp_xor2(acc[j]);
        }
        // ---- in-thread LSTM update (replicated x4 per quad) ----
        float gi = fast_sigmoid(acc[0] + fmaf(xv, wih[0], bias[0]));
        float gf = fast_sigmoid(acc[1] + fmaf(xv, wih[1], bias[1]));
        float gg = fast_tanh   (acc[2] + fmaf(xv, wih[2], bias[2]));
        float go = fast_sigmoid(acc[3] + fmaf(xv, wih[3], bias[3]));
        c = fmaf(gf, c, gi * gg);
        float hn = go * fast_tanh(c);

        const int rw = t & (CHUNK - 1);
        if (q == 0) h_hist[rw * HP + u] = hn;             // one lane per unit writes
        __syncthreads();                                  // the ONLY per-step barrier
        hrow_rd = h_hist + rw * HP;

        // ---- fused MLP head every CHUNK steps ----
        if (rw == (CHUNK - 1)) {
            int tbase = t - (CHUNK - 1);
            int tl = tid >> 3, j0 = tid & 7;              // 32 t-rows x 8 j-lanes
            float4 hh[16];
            const float4* hr = (const float4*)(h_hist + tl * HP);
            #pragma unroll
            for (int m = 0; m < 16; ++m) hh[m] = hr[m];
            float xc = x_lds[tbase + tl];
            #pragma unroll
            for (int jj = 0; jj < 5; ++jj) {
                int j = j0 + 8 * jj;
                const float4* w1r = (const float4*)(w1_lds + j * W1P);
                float a0 = b1_lds[j], a1 = 0.f, a2 = 0.f, a3 = 0.f;
                #pragma unroll
                for (int m = 0; m < 16; ++m) {
                    float4 wv = w1r[m];
                    a0 = fmaf(hh[m].x, wv.x, a0);
                    a1 = fmaf(hh[m].y, wv.y, a1);
                    a2 = fmaf(hh[m].z, wv.z, a2);
                    a3 = fmaf(hh[m].w, wv.w, a3);
                }
                float zacc = ((a0 + a1) + (a2 + a3)) + xc * w1_lds[j * W1P + 64];
                z_lds[tl * ZP + j] = fast_sigmoid(zacc);
            }
            __syncthreads();
            if (tid < CHUNK) {                            // 32 lanes reduce 40 z's
                float y = b2v;
                #pragma unroll
                for (int j = 0; j < MLP_HID; ++j)
                    y = fmaf(w2_lds[j], z_lds[tid * ZP + j], y);
                outb[tbase + tid] = y;
            }
            // next h_hist write (row 0) happens after the mid-MLP barrier;
            // hh/z reads are already done by then — no trailing barrier needed.
        }
    }
}

extern "C" void kernel_launch(void* const* d_in, const int* in_sizes, int n_in,
                              void* d_out, int out_size, void* d_ws, size_t ws_size,
                              hipStream_t stream) {
    const float* inputs = (const float*)d_in[0];
    const float* W_ih   = (const float*)d_in[1];
    const float* W_hh   = (const float*)d_in[2];
    const float* b_ih   = (const float*)d_in[3];
    const float* b_hh   = (const float*)d_in[4];
    const float* W1     = (const float*)d_in[5];
    const float* b1     = (const float*)d_in[6];
    const float* W2     = (const float*)d_in[7];
    const float* b2     = (const float*)d_in[8];
    float* out = (float*)d_out;

    lstm_mlp_kernel<<<dim3(256), dim3(256), 0, stream>>>(
        inputs, W_ih, W_hh, b_ih, b_hh, W1, b1, W2, b2, out);
}

// Round 3
// 1468.662 us; speedup vs baseline: 1.6079x; 1.1770x over previous
//
#include <hip/hip_runtime.h>

#define HIDDEN  64
#define T_LEN   4096
#define CHUNK   32
#define MLP_HID 40
#define HP      68      // h_hist row pitch (floats)
#define W1P     68      // W1 LDS row pitch
#define ZP      41      // z LDS row pitch

typedef float v2f __attribute__((ext_vector_type(2)));

__device__ __forceinline__ v2f pk_fma(v2f a, v2f b, v2f c) {
    v2f d;
    asm("v_pk_fma_f32 %0, %1, %2, %3" : "=v"(d) : "v"(a), "v"(b), "v"(c));
    return d;
}

__device__ __forceinline__ float fast_sigmoid(float x) {
    float e = __builtin_amdgcn_exp2f(x * -1.4426950408889634f);
    return __builtin_amdgcn_rcpf(1.0f + e);
}

// quad butterfly: xor1 = quad_perm[1,0,3,2]=0xB1, xor2 = [2,3,0,1]=0x4E
__device__ __forceinline__ float dpp_xor1(float v) {
    return __int_as_float(__builtin_amdgcn_update_dpp(
        0, __float_as_int(v), 0xB1, 0xF, 0xF, true));
}
__device__ __forceinline__ float dpp_xor2(float v) {
    return __int_as_float(__builtin_amdgcn_update_dpp(
        0, __float_as_int(v), 0x4E, 0xF, 0xF, true));
}

__global__ __launch_bounds__(256, 1)
void lstm_mlp_kernel(const float* __restrict__ inputs,
                     const float* __restrict__ W_ih,
                     const float* __restrict__ W_hh,
                     const float* __restrict__ b_ih,
                     const float* __restrict__ b_hh,
                     const float* __restrict__ W1,
                     const float* __restrict__ b1,
                     const float* __restrict__ W2,
                     const float* __restrict__ b2,
                     float* __restrict__ out)
{
    __shared__ __align__(16) float x_lds[T_LEN];
    __shared__ __align__(16) float h_hist[CHUNK * HP];
    __shared__ __align__(16) float w1_lds[MLP_HID * W1P];
    __shared__ float b1_lds[MLP_HID];
    __shared__ float w2_lds[MLP_HID];
    __shared__ float z_lds[CHUNK * ZP];

    const int tid = threadIdx.x;
    const int b   = blockIdx.x;
    const int w   = tid >> 6;        // wave 0..3
    const int l   = tid & 63;
    const int r   = l >> 2;          // unit-in-wave 0..15
    const int q   = l & 3;           // quad role: gate type AND K-chunk
    const int u   = 16 * w + r;      // hidden unit owned by this quad
    const bool q1 = (q & 1) != 0;
    const bool q2 = (q & 2) != 0;

    // ---- prologue ----
    const float4* in4 = (const float4*)(inputs + (size_t)b * T_LEN);
    float4* x4 = (float4*)x_lds;
    #pragma unroll
    for (int rr = 0; rr < 4; ++rr) x4[tid + 256 * rr] = in4[tid + 256 * rr];

    // W_hh[j*64+u][16q .. 16q+16) as float2 pairs, for all 4 gate types j
    v2f wq2[4][8];
    #pragma unroll
    for (int j = 0; j < 4; ++j) {
        const float4* p = (const float4*)(W_hh + (j * 64 + u) * HIDDEN + 16 * q);
        #pragma unroll
        for (int m = 0; m < 4; ++m) {
            float4 t = p[m];
            wq2[j][2 * m]     = (v2f){t.x, t.y};
            wq2[j][2 * m + 1] = (v2f){t.z, t.w};
        }
    }
    // this lane's own gate (type q, unit u): x-weight, bias, activation consts
    const int   gown = q * 64 + u;
    const float wq   = W_ih[gown];
    const float bq   = b_ih[gown] + b_hh[gown];
    const float m_c  = (q == 2) ?  2.8853900817779268f : -1.4426950408889634f;
    const float a_c  = (q == 2) ? -2.0f : 1.0f;
    const float d_c  = (q == 2) ?  1.0f : 0.0f;
    const float b2v  = b2[0];

    for (int p = tid; p < MLP_HID * 65; p += 256) {
        int row = p / 65, col = p - row * 65;
        w1_lds[row * W1P + col] = W1[p];
    }
    if (tid < MLP_HID) { b1_lds[tid] = b1[tid]; w2_lds[tid] = W2[tid]; }
    if (tid < HIDDEN)  h_hist[31 * HP + tid] = 0.0f;   // h(-1) in row 31
    float c = 0.0f;
    __syncthreads();

    float* outb = out + (size_t)b * T_LEN;

    for (int tc = 0; tc < T_LEN / CHUNK; ++tc) {
        #pragma unroll 2
        for (int tt = 0; tt < CHUNK; ++tt) {
            const int t  = tc * CHUNK + tt;
            const int rw = tt;
            const float* hrow = h_hist + ((tt + CHUNK - 1) & (CHUNK - 1)) * HP;

            float xv = x_lds[t];
            // ---- gate partials (pk fp32): 4 gates x 16-K slice ----
            v2f hv[8];
            const float4* h4 = (const float4*)(hrow + 16 * q);
            #pragma unroll
            for (int m = 0; m < 4; ++m) {
                float4 tv = h4[m];
                hv[2 * m]     = (v2f){tv.x, tv.y};
                hv[2 * m + 1] = (v2f){tv.z, tv.w};
            }
            float acc[4];
            #pragma unroll
            for (int j = 0; j < 4; ++j) {
                v2f a = {0.f, 0.f}, bb = {0.f, 0.f};
                #pragma unroll
                for (int m = 0; m < 4; ++m) {
                    a  = pk_fma(hv[2 * m],     wq2[j][2 * m],     a);
                    bb = pk_fma(hv[2 * m + 1], wq2[j][2 * m + 1], bb);
                }
                v2f s2 = a + bb;
                acc[j] = s2.x + s2.y;
            }
            // ---- butterfly stage 1 on all gates ----
            #pragma unroll
            for (int j = 0; j < 4; ++j) acc[j] += dpp_xor1(acc[j]);
            // per-lane select own-gate + xor2-partner-gate stage-1 sums
            float t0 = q1 ? acc[1] : acc[0];
            float t1 = q1 ? acc[3] : acc[2];
            float s_own  = q2 ? t1 : t0;
            float s_part = q2 ? t0 : t1;
            float tot = s_own + dpp_xor2(s_part);   // full sum of gate q
            // ---- single activation per lane (divergence-free unified form) ----
            float pre = tot + fmaf(xv, wq, bq);
            float act = fmaf(a_c, __builtin_amdgcn_rcpf(
                              1.0f + __builtin_amdgcn_exp2f(m_c * pre)), d_c);
            // ---- quad exchange: i*g to all, f to all ----
            float recv = dpp_xor2(act);             // 0:g 1:o 2:i 3:f
            float p  = act * recv;                  // lanes 0,2: i*g
            float e0 = q2 ? recv : act;             // f for odd lanes
            float e  = q1 ? e0 : p;
            float rr = dpp_xor1(e);
            float fv = q1 ? e : rr;
            float ig = q1 ? rr : e;
            c = fmaf(fv, c, ig);
            float th = fmaf(-2.0f, __builtin_amdgcn_rcpf(
                             1.0f + __builtin_amdgcn_exp2f(2.8853900817779268f * c)), 1.0f);
            float ov = q2 ? act : recv;             // o for lanes 1,3
            float hn = ov * th;
            if (q == 1) h_hist[rw * HP + u] = hn;
            __syncthreads();
        }

        // ---- fused MLP head for this chunk ----
        {
            int tbase = tc * CHUNK;
            int tl = tid >> 3, j0 = tid & 7;
            float4 hh[16];
            const float4* hr = (const float4*)(h_hist + tl * HP);
            #pragma unroll
            for (int m = 0; m < 16; ++m) hh[m] = hr[m];
            float xc = x_lds[tbase + tl];
            #pragma unroll
            for (int jj = 0; jj < 5; ++jj) {
                int j = j0 + 8 * jj;
                const float4* w1r = (const float4*)(w1_lds + j * W1P);
                float a0 = b1_lds[j], a1 = 0.f, a2 = 0.f, a3 = 0.f;
                #pragma unroll
                for (int m = 0; m < 16; ++m) {
                    float4 wv = w1r[m];
                    a0 = fmaf(hh[m].x, wv.x, a0);
                    a1 = fmaf(hh[m].y, wv.y, a1);
                    a2 = fmaf(hh[m].z, wv.z, a2);
                    a3 = fmaf(hh[m].w, wv.w, a3);
                }
                float zacc = ((a0 + a1) + (a2 + a3)) + xc * w1_lds[j * W1P + 64];
                z_lds[tl * ZP + j] = fast_sigmoid(zacc);
            }
            __syncthreads();
            if (tid < CHUNK) {
                float y = b2v;
                #pragma unroll
                for (int j = 0; j < MLP_HID; ++j)
                    y = fmaf(w2_lds[j], z_lds[tid * ZP + j], y);
                outb[tbase + tid] = y;
            }
            // next h_hist write (row 0) comes after the mid-MLP barrier and the
            // hh/z values are already consumed — no trailing barrier needed.
        }
    }
}

extern "C" void kernel_launch(void* const* d_in, const int* in_sizes, int n_in,
                              void* d_out, int out_size, void* d_ws, size_t ws_size,
                              hipStream_t stream) {
    const float* inputs = (const float*)d_in[0];
    const float* W_ih   = (const float*)d_in[1];
    const float* W_hh   = (const float*)d_in[2];
    const float* b_ih   = (const float*)d_in[3];
    const float* b_hh   = (const float*)d_in[4];
    const float* W1     = (const float*)d_in[5];
    const float* b1     = (const float*)d_in[6];
    const float* W2     = (const float*)d_in[7];
    const float* b2     = (const float*)d_in[8];
    float* out = (float*)d_out;

    lstm_mlp_kernel<<<dim3(256), dim3(256), 0, stream>>>(
        inputs, W_ih, W_hh, b_ih, b_hh, W1, b1, W2, b2, out);
}

// Round 5
// 1428.392 us; speedup vs baseline: 1.6532x; 1.0282x over previous
//
#include <hip/hip_runtime.h>

#define HIDDEN  64
#define T_LEN   4096
#define CHUNK   32
#define MLP_HID 40
#define HP      68      // h_hist row pitch (floats)
#define W1P     68
#define ZP      41

typedef float v2f __attribute__((ext_vector_type(2)));
typedef float v4f __attribute__((ext_vector_type(4)));

#define LO2(x) __builtin_shufflevector(x, x, 0, 1)
#define HI2(x) __builtin_shufflevector(x, x, 2, 3)

__device__ __forceinline__ v2f pk_fma(v2f a, v2f b, v2f c) {
    v2f d;
    asm("v_pk_fma_f32 %0, %1, %2, %3" : "=v"(d) : "v"(a), "v"(b), "v"(c));
    return d;
}
// cross-lane via builtins ONLY (compiler inserts DPP hazard wait-states;
// raw v_add_f32_dpp asm caused a numerics failure in round 3)
__device__ __forceinline__ float dpp_x1(float v) {   // quad_perm [1,0,3,2]
    return __int_as_float(__builtin_amdgcn_update_dpp(
        0, __float_as_int(v), 0xB1, 0xF, 0xF, true));
}
__device__ __forceinline__ float dpp_x2(float v) {   // quad_perm [2,3,0,1]
    return __int_as_float(__builtin_amdgcn_update_dpp(
        0, __float_as_int(v), 0x4E, 0xF, 0xF, true));
}
__device__ __forceinline__ float fast_sigmoid(float x) {
    float e = __builtin_amdgcn_exp2f(x * -1.4426950408889634f);
    return __builtin_amdgcn_rcpf(1.0f + e);
}

__global__ __launch_bounds__(256, 1)
void lstm_mlp_kernel(const float* __restrict__ inputs,
                     const float* __restrict__ W_ih,
                     const float* __restrict__ W_hh,
                     const float* __restrict__ b_ih,
                     const float* __restrict__ b_hh,
                     const float* __restrict__ W1,
                     const float* __restrict__ b1,
                     const float* __restrict__ W2,
                     const float* __restrict__ b2,
                     float* __restrict__ out)
{
    __shared__ __align__(16) float x_lds[T_LEN];
    __shared__ __align__(16) float h_hist[CHUNK * HP];
    __shared__ __align__(16) float w1_lds[MLP_HID * W1P];
    __shared__ float b1_lds[MLP_HID];
    __shared__ float w2_lds[MLP_HID];
    __shared__ float z_lds[CHUNK * ZP];

    const int tid = threadIdx.x;
    const int b   = blockIdx.x;
    const int w   = tid >> 6;
    const int l   = tid & 63;
    const int r   = l >> 2;
    const int q   = l & 3;           // quad role: gate type AND K-chunk
    const int u   = 16 * w + r;      // hidden unit owned by this quad
    const bool q1 = (q & 1) != 0;
    const bool q2 = (q & 2) != 0;
    const bool wlane = (q == 1);

    // ---- prologue ----
    const float4* in4 = (const float4*)(inputs + (size_t)b * T_LEN);
    float4* x4 = (float4*)x_lds;
    #pragma unroll
    for (int rr = 0; rr < 4; ++rr) x4[tid + 256 * rr] = in4[tid + 256 * rr];

    // W_hh[j*64+u][16q .. 16q+16) as 8 v2f per gate type j
    v2f wq2[4][8];
    #pragma unroll
    for (int j = 0; j < 4; ++j) {
        const float4* p = (const float4*)(W_hh + (j * 64 + u) * HIDDEN + 16 * q);
        #pragma unroll
        for (int m = 0; m < 4; ++m) {
            float4 t = p[m];
            wq2[j][2 * m]     = (v2f){t.x, t.y};
            wq2[j][2 * m + 1] = (v2f){t.z, t.w};
        }
    }
    // own gate (type q, unit u) — round-2 exact numerics (no constant folding)
    const int   gown = q * 64 + u;
    const float wq   = W_ih[gown];
    const float bq   = b_ih[gown] + b_hh[gown];
    const float m_c  = (q == 2) ?  2.8853900817779268f : -1.4426950408889634f;
    const float a_c  = (q == 2) ? -2.0f : 1.0f;
    const float d_c  = (q == 2) ?  1.0f : 0.0f;
    const float b2v  = b2[0];

    for (int p = tid; p < MLP_HID * 65; p += 256) {
        int row = p / 65, col = p - row * 65;
        w1_lds[row * W1P + col] = W1[p];
    }
    if (tid < MLP_HID) { b1_lds[tid] = b1[tid]; w2_lds[tid] = W2[tid]; }
    if (tid < HIDDEN)  h_hist[31 * HP + tid] = 0.0f;   // h(-1) in row 31
    float c = 0.0f;
    __syncthreads();

    float* outb = out + (size_t)b * T_LEN;
    const float* hq_base = h_hist + 16 * q;   // this lane's K-slice base
    float*       hwp     = h_hist + u;        // this lane's write column

    for (int tc = 0; tc < T_LEN / CHUNK; ++tc) {
        const float* xcb = x_lds + tc * CHUNK;

        #pragma unroll
        for (int tt = 0; tt < CHUNK; ++tt) {
            const int rp = (tt + CHUNK - 1) & (CHUNK - 1);  // compile-time row
            const v4f* h4 = (const v4f*)(hq_base + rp * HP);
            v4f ha = h4[0], hb = h4[1], hc = h4[2], hd = h4[3];
            float xv = xcb[tt];

            float acc[4];
            #pragma unroll
            for (int j = 0; j < 4; ++j) {
                v2f p0 = LO2(ha) * wq2[j][0];
                v2f p1 = HI2(ha) * wq2[j][1];
                p0 = pk_fma(LO2(hb), wq2[j][2], p0);
                p1 = pk_fma(HI2(hb), wq2[j][3], p1);
                p0 = pk_fma(LO2(hc), wq2[j][4], p0);
                p1 = pk_fma(HI2(hc), wq2[j][5], p1);
                p0 = pk_fma(LO2(hd), wq2[j][6], p0);
                p1 = pk_fma(HI2(hd), wq2[j][7], p1);
                v2f s = p0 + p1;
                acc[j] = s.x + s.y;
            }
            // butterfly stage 1 (builtin DPP), per-lane select, stage 2
            #pragma unroll
            for (int j = 0; j < 4; ++j) acc[j] += dpp_x1(acc[j]);
            float t0 = q1 ? acc[1] : acc[0];
            float t1 = q1 ? acc[3] : acc[2];
            float s_own  = q2 ? t1 : t0;
            float s_part = q2 ? t0 : t1;
            float tot = s_own + dpp_x2(s_part);    // full own-gate sum

            // single activation per lane (round-2 exact form)
            float pre = tot + fmaf(xv, wq, bq);
            float act = fmaf(a_c, __builtin_amdgcn_rcpf(
                              1.0f + __builtin_amdgcn_exp2f(m_c * pre)), d_c);

            // quad exchange: f and i*g to all lanes (lane q==1 keeps o)
            float recv = dpp_x2(act);              // 0:g 1:o 2:i 3:f
            float p    = act * recv;               // lanes 0,2: i*g
            float e0 = q2 ? recv : act;
            float e  = q1 ? e0 : p;
            float rr = dpp_x1(e);
            float fv = q1 ? e : rr;
            float ig = q1 ? rr : e;
            c = fmaf(fv, c, ig);
            float th = fmaf(-2.0f, __builtin_amdgcn_rcpf(
                             1.0f + __builtin_amdgcn_exp2f(2.8853900817779268f * c)), 1.0f);
            float ov = q2 ? act : recv;            // o (valid on lane q==1)
            float hn = ov * th;
            if (wlane) hwp[tt * HP] = hn;
            __syncthreads();
        }

        // ---- fused MLP head for this chunk ----
        {
            int tbase = tc * CHUNK;
            int tl = tid >> 3, j0 = tid & 7;
            float4 hh[16];
            const float4* hr = (const float4*)(h_hist + tl * HP);
            #pragma unroll
            for (int m = 0; m < 16; ++m) hh[m] = hr[m];
            float xc = x_lds[tbase + tl];
            #pragma unroll
            for (int jj = 0; jj < 5; ++jj) {
                int j = j0 + 8 * jj;
                const float4* w1r = (const float4*)(w1_lds + j * W1P);
                float a0 = b1_lds[j], a1 = 0.f, a2 = 0.f, a3 = 0.f;
                #pragma unroll
                for (int m = 0; m < 16; ++m) {
                    float4 wv = w1r[m];
                    a0 = fmaf(hh[m].x, wv.x, a0);
                    a1 = fmaf(hh[m].y, wv.y, a1);
                    a2 = fmaf(hh[m].z, wv.z, a2);
                    a3 = fmaf(hh[m].w, wv.w, a3);
                }
                float zacc = ((a0 + a1) + (a2 + a3)) + xc * w1_lds[j * W1P + 64];
                z_lds[tl * ZP + j] = fast_sigmoid(zacc);
            }
            __syncthreads();
            if (tid < CHUNK) {
                float y = b2v;
                #pragma unroll
                for (int j = 0; j < MLP_HID; ++j)
                    y = fmaf(w2_lds[j], z_lds[tid * ZP + j], y);
                outb[tbase + tid] = y;
            }
            // next h_hist write (row 0) is fenced by the mid-MLP barrier;
            // hh/z values are already consumed — no trailing barrier needed.
        }
    }
}

extern "C" void kernel_launch(void* const* d_in, const int* in_sizes, int n_in,
                              void* d_out, int out_size, void* d_ws, size_t ws_size,
                              hipStream_t stream) {
    const float* inputs = (const float*)d_in[0];
    const float* W_ih   = (const float*)d_in[1];
    const float* W_hh   = (const float*)d_in[2];
    const float* b_ih   = (const float*)d_in[3];
    const float* b_hh   = (const float*)d_in[4];
    const float* W1     = (const float*)d_in[5];
    const float* b1     = (const float*)d_in[6];
    const float* W2     = (const float*)d_in[7];
    const float* b2     = (const float*)d_in[8];
    float* out = (float*)d_out;

    lstm_mlp_kernel<<<dim3(256), dim3(256), 0, stream>>>(
        inputs, W_ih, W_hh, b_ih, b_hh, W1, b1, W2, b2, out);
}